// Round 18
// baseline (314.939 us; speedup 1.0000x reference)
//
#include <hip/hip_runtime.h>
#include <hip/hip_bf16.h>

typedef __attribute__((ext_vector_type(8))) __bf16 bf16x8;
typedef __attribute__((ext_vector_type(4))) float f32x4;

// ---------------- prep: hist + W transpose + M^T/bM + m2/c0 ----------------
// Wt layout [c][k], c in [0,640): 0..127 = M^T, 128..511 = Wkv^T, 512..639 = Wvec^T

__global__ void prep_kernel(const int* __restrict__ row, int* __restrict__ cnt, int e,
                            const float* __restrict__ Wq, const float* __restrict__ Wkv,
                            const float* __restrict__ Wvec, const float* __restrict__ bq,
                            const float* __restrict__ bkv,
                            __bf16* __restrict__ Wt, float* __restrict__ bM,
                            float* __restrict__ m2, float* __restrict__ c0, int nbh) {
  const int bid = blockIdx.x, tid = threadIdx.x;
  if (bid < nbh) {
    int i = bid * 256 + tid;
    if (i < e) atomicAdd(&cnt[row[i]], 1);
  } else if (bid < nbh + 256) {
    int idx = (bid - nbh) * 256 + tid;   // 512*128
    int c = 128 + (idx >> 7), k = idx & 127;
    float w = (c < 512) ? Wkv[k * 384 + (c - 128)] : Wvec[k * 128 + (c - 512)];
    Wt[c * 128 + k] = (__bf16)w;
  } else if (bid < nbh + 256 + 128) {
    __shared__ float wk[128];
    int c = bid - (nbh + 256);
    if (tid < 128) wk[tid] = Wkv[c * 384 + tid];
    __syncthreads();
    if (tid < 128) {
      float acc = 0.f;
      #pragma unroll 8
      for (int j = 0; j < 128; j++) acc += Wq[tid * 128 + j] * wk[j];
      Wt[c * 128 + tid] = (__bf16)acc;
    } else if (tid == 128) {
      float acc = 0.f;
      for (int j = 0; j < 128; j++) acc += bq[j] * wk[j];
      bM[c] = acc;
    }
  } else {
    if (tid < 128) {
      float acc = 0.f;
      for (int j = 0; j < 128; j++) acc += Wq[tid * 128 + j] * bkv[j];
      m2[tid] = acc;
    } else if (tid == 128) {
      float acc = 0.f;
      for (int j = 0; j < 128; j++) acc += bq[j] * bkv[j];
      c0[0] = acc;
    }
  }
}

__global__ __launch_bounds__(1024) void scan1_kernel(const int* __restrict__ cnt, int* __restrict__ off,
                                                     int* __restrict__ bsum, int n) {
  __shared__ int sh[1024];
  int tid = threadIdx.x;
  int i = blockIdx.x * 1024 + tid;
  int v = (i < n) ? cnt[i] : 0;
  sh[tid] = v;
  __syncthreads();
  for (int d = 1; d < 1024; d <<= 1) {
    int t = (tid >= d) ? sh[tid - d] : 0;
    __syncthreads();
    sh[tid] += t;
    __syncthreads();
  }
  if (i < n) off[i] = sh[tid] - v;
  if (tid == 1023) bsum[blockIdx.x] = sh[1023];
}

__global__ __launch_bounds__(1024) void scan3_kernel(const int* __restrict__ bsum, int* __restrict__ off,
                                                     int* __restrict__ cursor, int n, int e) {
  __shared__ int base_sh;
  const int tid = threadIdx.x;
  if (tid < 64) {
    int part = 0;
    for (int b = tid; b < (int)blockIdx.x; b += 64) part += bsum[b];
    #pragma unroll
    for (int m = 32; m >= 1; m >>= 1) part += __shfl_xor(part, m);
    if (tid == 0) base_sh = part;
  }
  __syncthreads();
  const int base = base_sh;
  int i = blockIdx.x * 1024 + tid;
  if (i < n) { int o = off[i] + base; off[i] = o; cursor[i] = o; }
  if (i == 0) off[n] = e;
}

// ---------------- GEMM1 + scatter merged (512 threads, 128 rows/block, bf16 sO) ----------------
// gemm1: y=0 -> qM(+beta); y=1 -> sbf | P = (s@Wvv+bvv)*v.  nodebuf/node: [sbf|P0|P1|P2] bf16.

__global__ __launch_bounds__(512, 8) void gemm1_scatter(
    const int* __restrict__ row, const int* __restrict__ col,
    int* __restrict__ cursor, int* __restrict__ scol, int e, int ngemm,
    const float* __restrict__ s, const __bf16* __restrict__ Wtg,
    const float* __restrict__ bM, const float* __restrict__ bkv,
    const float* __restrict__ m2, const float* __restrict__ c0,
    const float* __restrict__ v,
    __bf16* __restrict__ qb, float* __restrict__ beta,
    __bf16* __restrict__ nodebuf, int n)
{
  __shared__ char uB[34816];                 // union: sB (bf16[128][136]) / sO16 (bf16[128][136])
  __bf16* sB = (__bf16*)uB;
  __bf16* sO = (__bf16*)uB;

  const int tid = threadIdx.x;
  if ((int)blockIdx.x >= ngemm) {            // -------- scatter part --------
    int i = ((int)blockIdx.x - ngemm) * 512 + tid;
    if (i < e) { int r = row[i]; int pos = atomicAdd(&cursor[r], 1); scol[pos] = col[i]; }
    return;
  }

  const int nb1 = (n + 127) >> 7;
  const int y = ((int)blockIdx.x < nb1) ? 0 : 1;
  const int n0 = (y == 0 ? (int)blockIdx.x : (int)blockIdx.x - nb1) * 128;
  const int wave = tid >> 6, lane = tid & 63;
  const int lr = lane & 15, lg = lane >> 4;
  const int arow = n0 + wave * 16 + lr;

  { // stage W^T chunk: 512 threads, each 32 bf16 of one row
    int r2 = tid >> 2, q = tid & 3;
    const __bf16* src = &Wtg[(size_t)((y == 0 ? 0 : 384) + r2) * 128 + q * 32];
    #pragma unroll
    for (int i = 0; i < 4; i++)
      *(bf16x8*)&sB[r2 * 136 + q * 32 + i * 8] = *(const bf16x8*)&src[i * 8];
  }

  bf16x8 a[4];
  if (arow < n) {
    #pragma unroll
    for (int ks = 0; ks < 4; ks++) {
      float4 f0 = *(const float4*)&s[(size_t)arow * 128 + ks * 32 + lg * 8];
      float4 f1 = *(const float4*)&s[(size_t)arow * 128 + ks * 32 + lg * 8 + 4];
      bf16x8 pk;
      pk[0] = (__bf16)f0.x; pk[1] = (__bf16)f0.y; pk[2] = (__bf16)f0.z; pk[3] = (__bf16)f0.w;
      pk[4] = (__bf16)f1.x; pk[5] = (__bf16)f1.y; pk[6] = (__bf16)f1.z; pk[7] = (__bf16)f1.w;
      a[ks] = pk;
    }
  } else {
    #pragma unroll
    for (int ks = 0; ks < 4; ks++) a[ks] = bf16x8{0,0,0,0,0,0,0,0};
  }
  __syncthreads();

  f32x4 acc[8];
  #pragma unroll
  for (int cf = 0; cf < 8; cf++) {
    f32x4 c = {0.f, 0.f, 0.f, 0.f};
    #pragma unroll
    for (int ks = 0; ks < 4; ks++) {
      bf16x8 b = *(const bf16x8*)&sB[(cf * 16 + lr) * 136 + ks * 32 + lg * 8];
      c = __builtin_amdgcn_mfma_f32_16x16x32_bf16(a[ks], b, c, 0, 0, 0);
    }
    acc[cf] = c;
  }
  __syncthreads();   // done reading sB

  #pragma unroll
  for (int cf = 0; cf < 8; cf++) {
    int cl = cf * 16 + lr;
    #pragma unroll
    for (int r = 0; r < 4; r++)
      sO[(wave * 16 + lg * 4 + r) * 136 + cl] = (__bf16)acc[cf][r];
  }
  __syncthreads();

  const int drow = tid >> 2, dseg = tid & 3;
  const int dgn = n0 + drow;

  if (y == 0) {
    float part = 0.f;
    #pragma unroll
    for (int ks = 0; ks < 4; ks++)
      #pragma unroll
      for (int j = 0; j < 8; j++)
        part += (float)a[ks][j] * m2[ks * 32 + lg * 8 + j];
    part += __shfl_xor(part, 16);
    part += __shfl_xor(part, 32);
    if (lane < 16 && arow < n) beta[arow] = part + c0[0];

    if (dgn < n) {
      #pragma unroll
      for (int i = 0; i < 4; i++) {
        int cc = dseg * 32 + i * 8;
        bf16x8 pk;
        #pragma unroll
        for (int j = 0; j < 8; j++)
          pk[j] = (__bf16)((float)sO[drow * 136 + cc + j] + bM[cc + j]);
        *(bf16x8*)&qb[(size_t)dgn * 128 + cc] = pk;
      }
    }
  } else {
    if (arow < n) {
      #pragma unroll
      for (int ks = 0; ks < 4; ks++)
        *(bf16x8*)&nodebuf[(size_t)arow * 512 + ks * 32 + lg * 8] = a[ks];
    }
    if (dgn < n) {
      float vv[32];
      #pragma unroll
      for (int j = 0; j < 32; j++)
        vv[j] = (float)sO[drow * 136 + dseg * 32 + j] + bkv[256 + dseg * 32 + j];
      #pragma unroll
      for (int j3 = 0; j3 < 3; j3++) {
        #pragma unroll
        for (int i = 0; i < 4; i++) {
          int cc = dseg * 32 + i * 8;
          float4 va = *(const float4*)&v[((size_t)dgn * 3 + j3) * 128 + cc];
          float4 vb = *(const float4*)&v[((size_t)dgn * 3 + j3) * 128 + cc + 4];
          bf16x8 pk;
          pk[0] = (__bf16)(vv[i*8+0] * va.x); pk[1] = (__bf16)(vv[i*8+1] * va.y);
          pk[2] = (__bf16)(vv[i*8+2] * va.z); pk[3] = (__bf16)(vv[i*8+3] * va.w);
          pk[4] = (__bf16)(vv[i*8+4] * vb.x); pk[5] = (__bf16)(vv[i*8+5] * vb.y);
          pk[6] = (__bf16)(vv[i*8+6] * vb.z); pk[7] = (__bf16)(vv[i*8+7] * vb.w);
          *(bf16x8*)&nodebuf[(size_t)dgn * 512 + 128 + j3 * 128 + cc] = pk;
        }
      }
    }
  }
}

// ---------------- Aggregation (unchanged) ----------------

__device__ inline float2 bf2f(unsigned u) {
  float2 r;
  r.x = __uint_as_float((u & 0xffffu) << 16);
  r.y = __uint_as_float(u & 0xffff0000u);
  return r;
}

__device__ __forceinline__ float dpp_add(float x, const int ctrl) {
  int t;
  switch (ctrl) {
    case 0:  t = __builtin_amdgcn_update_dpp(0, __float_as_int(x), 0xB1, 0xF, 0xF, true); break;
    case 1:  t = __builtin_amdgcn_update_dpp(0, __float_as_int(x), 0x4E, 0xF, 0xF, true); break;
    case 2:  t = __builtin_amdgcn_update_dpp(0, __float_as_int(x), 0x141, 0xF, 0xF, true); break;
    default: t = __builtin_amdgcn_update_dpp(0, __float_as_int(x), 0x140, 0xF, 0xF, true); break;
  }
  return x + __int_as_float(t);
}

__device__ __forceinline__ float row16_sum(float x) {
  x = dpp_add(x, 0); x = dpp_add(x, 1); x = dpp_add(x, 2); x = dpp_add(x, 3);
  return x;
}

#define ACCP(arr, vec) do { float2 _t;                                                \
  _t = bf2f(vec.x); arr[0].x = fmaf(d, _t.x, arr[0].x); arr[0].y = fmaf(d, _t.y, arr[0].y); \
  _t = bf2f(vec.y); arr[1].x = fmaf(d, _t.x, arr[1].x); arr[1].y = fmaf(d, _t.y, arr[1].y); \
  _t = bf2f(vec.z); arr[2].x = fmaf(d, _t.x, arr[2].x); arr[2].y = fmaf(d, _t.y, arr[2].y); \
  _t = bf2f(vec.w); arr[3].x = fmaf(d, _t.x, arr[3].x); arr[3].y = fmaf(d, _t.y, arr[3].y); \
} while (0)

__global__ __launch_bounds__(256) void agg_kernel(
    const int* __restrict__ off, const int* __restrict__ scol,
    const __bf16* __restrict__ qb, const float* __restrict__ beta,
    const char* __restrict__ nodebuf,
    __bf16* __restrict__ gb, float* __restrict__ W1,
    __bf16* __restrict__ aggv16, int n)
{
  const int wid = threadIdx.x >> 6;
  const int lane = threadIdx.x & 63;
  const int nid = blockIdx.x * 4 + wid;
  if (nid >= n) return;
  const int slot = lane >> 4;
  const int fl = lane & 15;

  float qf[8];
  {
    uint4 qu = *(const uint4*)&qb[(size_t)nid * 128 + fl * 8];
    float2 t;
    t = bf2f(qu.x); qf[0] = t.x; qf[1] = t.y;
    t = bf2f(qu.y); qf[2] = t.x; qf[3] = t.y;
    t = bf2f(qu.z); qf[4] = t.x; qf[5] = t.y;
    t = bf2f(qu.w); qf[6] = t.x; qf[7] = t.y;
  }
  const float betar = beta[nid];

  float2 g[4], a0[4], a1[4], a2[4];
  float ws = 0.f;
  #pragma unroll
  for (int i = 0; i < 4; i++) {
    g[i] = make_float2(0.f, 0.f); a0[i] = make_float2(0.f, 0.f);
    a1[i] = make_float2(0.f, 0.f); a2[i] = make_float2(0.f, 0.f);
  }

  const int beg = off[nid];
  const int deg = off[nid + 1] - beg;

  for (int chunk = 0; chunk < deg; chunk += 64) {
    const int cc = (deg - chunk < 64) ? (deg - chunk) : 64;
    int myc = (lane < cc) ? scol[beg + chunk + lane] : 0;

    int c0i = __shfl(myc, (slot < cc) ? slot : 0);
    const char* gp = nodebuf + (size_t)c0i * 1024 + fl * 16;
    uint4 sc = *(const uint4*)(gp);
    uint4 p0 = *(const uint4*)(gp + 256);
    uint4 p1 = *(const uint4*)(gp + 512);
    uint4 p2 = *(const uint4*)(gp + 768);

    for (int j = 0; j < cc; j += 4) {
      const bool more = (j + 4 < cc);
      uint4 nsc, np0, np1, np2;
      if (more) {
        int ni = j + 4 + slot;
        int cn = __shfl(myc, (ni < cc) ? ni : 0);
        const char* gn = nodebuf + (size_t)cn * 1024 + fl * 16;
        nsc = *(const uint4*)(gn);
        np0 = *(const uint4*)(gn + 256);
        np1 = *(const uint4*)(gn + 512);
        np2 = *(const uint4*)(gn + 768);
      }

      float2 t0 = bf2f(sc.x), t1 = bf2f(sc.y), t2 = bf2f(sc.z), t3 = bf2f(sc.w);
      float d = 0.f;
      d = fmaf(qf[0], t0.x, d); d = fmaf(qf[1], t0.y, d);
      d = fmaf(qf[2], t1.x, d); d = fmaf(qf[3], t1.y, d);
      d = fmaf(qf[4], t2.x, d); d = fmaf(qf[5], t2.y, d);
      d = fmaf(qf[6], t3.x, d); d = fmaf(qf[7], t3.y, d);
      d = row16_sum(d) + betar;
      if (j + slot >= cc) d = 0.f;

      g[0].x = fmaf(d, t0.x, g[0].x); g[0].y = fmaf(d, t0.y, g[0].y);
      g[1].x = fmaf(d, t1.x, g[1].x); g[1].y = fmaf(d, t1.y, g[1].y);
      g[2].x = fmaf(d, t2.x, g[2].x); g[2].y = fmaf(d, t2.y, g[2].y);
      g[3].x = fmaf(d, t3.x, g[3].x); g[3].y = fmaf(d, t3.y, g[3].y);
      ws += d;
      ACCP(a0, p0); ACCP(a1, p1); ACCP(a2, p2);

      if (more) { sc = nsc; p0 = np0; p1 = np1; p2 = np2; }
    }
  }

  ws += __shfl_xor(ws, 16); ws += __shfl_xor(ws, 32);
  #pragma unroll
  for (int i = 0; i < 4; i++) {
    g[i].x  += __shfl_xor(g[i].x, 16);  g[i].x  += __shfl_xor(g[i].x, 32);
    g[i].y  += __shfl_xor(g[i].y, 16);  g[i].y  += __shfl_xor(g[i].y, 32);
    a0[i].x += __shfl_xor(a0[i].x, 16); a0[i].x += __shfl_xor(a0[i].x, 32);
    a0[i].y += __shfl_xor(a0[i].y, 16); a0[i].y += __shfl_xor(a0[i].y, 32);
    a1[i].x += __shfl_xor(a1[i].x, 16); a1[i].x += __shfl_xor(a1[i].x, 32);
    a1[i].y += __shfl_xor(a1[i].y, 16); a1[i].y += __shfl_xor(a1[i].y, 32);
    a2[i].x += __shfl_xor(a2[i].x, 16); a2[i].x += __shfl_xor(a2[i].x, 32);
    a2[i].y += __shfl_xor(a2[i].y, 16); a2[i].y += __shfl_xor(a2[i].y, 32);
  }

  if (slot == 0) {
    bf16x8 pk;
    pk[0] = (__bf16)g[0].x; pk[1] = (__bf16)g[0].y; pk[2] = (__bf16)g[1].x; pk[3] = (__bf16)g[1].y;
    pk[4] = (__bf16)g[2].x; pk[5] = (__bf16)g[2].y; pk[6] = (__bf16)g[3].x; pk[7] = (__bf16)g[3].y;
    *(bf16x8*)&gb[(size_t)nid * 128 + fl * 8] = pk;
    if (fl == 0) W1[nid] = ws;

    pk[0] = (__bf16)a0[0].x; pk[1] = (__bf16)a0[0].y; pk[2] = (__bf16)a0[1].x; pk[3] = (__bf16)a0[1].y;
    pk[4] = (__bf16)a0[2].x; pk[5] = (__bf16)a0[2].y; pk[6] = (__bf16)a0[3].x; pk[7] = (__bf16)a0[3].y;
    *(bf16x8*)&aggv16[((size_t)nid * 3 + 0) * 128 + fl * 8] = pk;
    pk[0] = (__bf16)a1[0].x; pk[1] = (__bf16)a1[0].y; pk[2] = (__bf16)a1[1].x; pk[3] = (__bf16)a1[1].y;
    pk[4] = (__bf16)a1[2].x; pk[5] = (__bf16)a1[2].y; pk[6] = (__bf16)a1[3].x; pk[7] = (__bf16)a1[3].y;
    *(bf16x8*)&aggv16[((size_t)nid * 3 + 1) * 128 + fl * 8] = pk;
    pk[0] = (__bf16)a2[0].x; pk[1] = (__bf16)a2[0].y; pk[2] = (__bf16)a2[1].x; pk[3] = (__bf16)a2[1].y;
    pk[4] = (__bf16)a2[2].x; pk[5] = (__bf16)a2[2].y; pk[6] = (__bf16)a2[3].x; pk[7] = (__bf16)a2[3].y;
    *(bf16x8*)&aggv16[((size_t)nid * 3 + 2) * 128 + fl * 8] = pk;
  }
}

// ---------------- GEMM23 (512 threads, 128 rows/block, bf16 sO) ----------------

__global__ __launch_bounds__(512, 8) void gemm23_mfma(
    const __bf16* __restrict__ Wtg, const float* __restrict__ bkv, const float* __restrict__ bvec,
    const float* __restrict__ s, const float* __restrict__ v,
    const __bf16* __restrict__ gb, const float* __restrict__ W1,
    const __bf16* __restrict__ aggv16,
    float* __restrict__ s_out, float* __restrict__ vout, int n, int nb1)
{
  __shared__ char uB[34816];
  __bf16* sB = (__bf16*)uB;
  __bf16* sO = (__bf16*)uB;

  const int tid = threadIdx.x;
  const bool smode = (int)blockIdx.x < nb1;
  const int r0 = (smode ? (int)blockIdx.x : (int)blockIdx.x - nb1) * 128;
  const int rows = smode ? n : 3 * n;
  const int wave = tid >> 6, lane = tid & 63;
  const int lr = lane & 15, lg = lane >> 4;
  const int arow = r0 + wave * 16 + lr;

  {
    int r2 = tid >> 2, q = tid & 3;
    const __bf16* src = &Wtg[(size_t)((smode ? 256 : 512) + r2) * 128 + q * 32];
    #pragma unroll
    for (int i = 0; i < 4; i++)
      *(bf16x8*)&sB[r2 * 136 + q * 32 + i * 8] = *(const bf16x8*)&src[i * 8];
  }

  const __bf16* Asrc = smode ? gb : aggv16;
  bf16x8 a[4];
  if (arow < rows) {
    #pragma unroll
    for (int ks = 0; ks < 4; ks++)
      a[ks] = *(const bf16x8*)&Asrc[(size_t)arow * 128 + ks * 32 + lg * 8];
  } else {
    #pragma unroll
    for (int ks = 0; ks < 4; ks++) a[ks] = bf16x8{0,0,0,0,0,0,0,0};
  }
  __syncthreads();

  f32x4 acc[8];
  #pragma unroll
  for (int cf = 0; cf < 8; cf++) {
    f32x4 c = {0.f, 0.f, 0.f, 0.f};
    #pragma unroll
    for (int ks = 0; ks < 4; ks++) {
      bf16x8 b = *(const bf16x8*)&sB[(cf * 16 + lr) * 136 + ks * 32 + lg * 8];
      c = __builtin_amdgcn_mfma_f32_16x16x32_bf16(a[ks], b, c, 0, 0, 0);
    }
    acc[cf] = c;
  }
  __syncthreads();

  #pragma unroll
  for (int cf = 0; cf < 8; cf++) {
    int cl = cf * 16 + lr;
    #pragma unroll
    for (int r = 0; r < 4; r++)
      sO[(wave * 16 + lg * 4 + r) * 136 + cl] = (__bf16)acc[cf][r];
  }
  __syncthreads();

  const int drow = tid >> 2, dseg = tid & 3;
  const int dgr = r0 + drow;

  if (dgr < rows) {
    if (smode) {
      const float w1 = W1[dgr];
      #pragma unroll
      for (int i = 0; i < 8; i++) {
        int cc = dseg * 32 + i * 4;
        float4 sa = *(const float4*)&s[(size_t)dgr * 128 + cc];
        float4 o;
        o.x = (float)sO[drow * 136 + cc + 0] + sa.x + w1 * bkv[128 + cc + 0];
        o.y = (float)sO[drow * 136 + cc + 1] + sa.y + w1 * bkv[128 + cc + 1];
        o.z = (float)sO[drow * 136 + cc + 2] + sa.z + w1 * bkv[128 + cc + 2];
        o.w = (float)sO[drow * 136 + cc + 3] + sa.w + w1 * bkv[128 + cc + 3];
        *(float4*)&s_out[(size_t)dgr * 128 + cc] = o;
      }
    } else {
      #pragma unroll
      for (int i = 0; i < 8; i++) {
        int cc = dseg * 32 + i * 4;
        float4 va = *(const float4*)&v[(size_t)dgr * 128 + cc];
        float4 o;
        o.x = (float)sO[drow * 136 + cc + 0] + va.x + bvec[cc + 0];
        o.y = (float)sO[drow * 136 + cc + 1] + va.y + bvec[cc + 1];
        o.z = (float)sO[drow * 136 + cc + 2] + va.z + bvec[cc + 2];
        o.w = (float)sO[drow * 136 + cc + 3] + va.w + bvec[cc + 3];
        *(float4*)&vout[(size_t)dgr * 128 + cc] = o;
      }
    }
  }
}

// ---------------- launch ----------------

extern "C" void kernel_launch(void* const* d_in, const int* in_sizes, int n_in,
                              void* d_out, int out_size, void* d_ws, size_t ws_size,
                              hipStream_t stream)
{
  const float* s    = (const float*)d_in[0];
  const float* v    = (const float*)d_in[1];
  const int*   ei   = (const int*)d_in[2];
  const float* Wq   = (const float*)d_in[3];
  const float* bq   = (const float*)d_in[4];
  const float* Wkv  = (const float*)d_in[5];
  const float* bkv  = (const float*)d_in[6];
  const float* Wvec = (const float*)d_in[7];
  const float* bvec = (const float*)d_in[8];

  const int N = in_sizes[0] / 128;
  const int E = in_sizes[2] / 2;
  const int* row = ei;
  const int* col = ei + E;

  char* ws = (char*)d_ws;
  size_t o = 0;
  auto alloc = [&](size_t bytes) -> char* {
    char* p = ws + o;
    o = (o + bytes + 255) & ~(size_t)255;
    return p;
  };
  int* off    = (int*)alloc((size_t)(N + 1) * 4);
  int* cursor = (int*)alloc((size_t)N * 4);
  int* bsum   = (int*)alloc(4096);
  int* scol   = (int*)alloc((size_t)E * 4);
  __bf16* qb      = (__bf16*)alloc((size_t)N * 128 * 2);
  float*  beta    = (float*)alloc((size_t)N * 4);
  float*  W1      = (float*)alloc((size_t)N * 4);
  __bf16* nodebuf = (__bf16*)alloc((size_t)N * 512 * 2);
  __bf16* Wt      = (__bf16*)alloc((size_t)640 * 128 * 2);
  __bf16* aggv16  = (__bf16*)alloc((size_t)N * 384 * 2);
  __bf16* gb      = (__bf16*)alloc((size_t)N * 128 * 2);
  float*  bM      = (float*)alloc(512);
  float*  m2      = (float*)alloc(512);
  float*  c0      = (float*)alloc(256);

  float* s_out = (float*)d_out;
  float* vout  = (float*)d_out + (size_t)N * 128;

  // prep: hist + W transpose + M^T + m2/c0
  (void)hipMemsetAsync(cursor, 0, (size_t)N * 4, stream);
  int nbh = (E + 255) / 256;
  prep_kernel<<<nbh + 256 + 128 + 1, 256, 0, stream>>>(row, cursor, E, Wq, Wkv, Wvec, bq, bkv,
                                                       Wt, bM, m2, c0, nbh);
  int nb = (N + 1023) / 1024;
  scan1_kernel<<<nb, 1024, 0, stream>>>(cursor, off, bsum, N);
  scan3_kernel<<<nb, 1024, 0, stream>>>(bsum, off, cursor, N, E);

  // gemm1 + scatter (merged; 512-thread blocks, gemm first)
  int nb1g = (N + 127) / 128;
  int ngemm = 2 * nb1g;
  int nbs_sc = (E + 511) / 512;
  gemm1_scatter<<<ngemm + nbs_sc, 512, 0, stream>>>(row, col, cursor, scol, E, ngemm,
                                                    s, Wt, bM, bkv, m2, c0, v,
                                                    qb, beta, nodebuf, N);

  // edge aggregation
  agg_kernel<<<(N + 3) / 4, 256, 0, stream>>>(off, scol, qb, beta, (const char*)nodebuf,
                                              gb, W1, aggv16, N);

  // fused output GEMMs (512-thread blocks)
  int nb1o = (N + 127) / 128;
  int nb2o = (3 * N + 127) / 128;
  gemm23_mfma<<<nb1o + nb2o, 512, 0, stream>>>(Wt, bkv, bvec, s, v, gb, W1, aggv16,
                                               s_out, vout, N, nb1o);
}

// Round 19
// 273.078 us; speedup vs baseline: 1.1533x; 1.1533x over previous
//
#include <hip/hip_runtime.h>
#include <hip/hip_bf16.h>

typedef __attribute__((ext_vector_type(8))) __bf16 bf16x8;
typedef __attribute__((ext_vector_type(4))) float f32x4;

// ---------------- prep: hist + W transpose + M^T/bM + m2/c0 ----------------
// Wt layout [c][k], c in [0,640): 0..127 = M^T, 128..511 = Wkv^T, 512..639 = Wvec^T

__global__ void prep_kernel(const int* __restrict__ row, int* __restrict__ cnt, int e,
                            const float* __restrict__ Wq, const float* __restrict__ Wkv,
                            const float* __restrict__ Wvec, const float* __restrict__ bq,
                            const float* __restrict__ bkv,
                            __bf16* __restrict__ Wt, float* __restrict__ bM,
                            float* __restrict__ m2, float* __restrict__ c0, int nbh) {
  const int bid = blockIdx.x, tid = threadIdx.x;
  if (bid < nbh) {
    int i = bid * 256 + tid;
    if (i < e) atomicAdd(&cnt[row[i]], 1);
  } else if (bid < nbh + 256) {
    int idx = (bid - nbh) * 256 + tid;   // 512*128
    int c = 128 + (idx >> 7), k = idx & 127;
    float w = (c < 512) ? Wkv[k * 384 + (c - 128)] : Wvec[k * 128 + (c - 512)];
    Wt[c * 128 + k] = (__bf16)w;
  } else if (bid < nbh + 256 + 128) {
    __shared__ float wk[128];
    int c = bid - (nbh + 256);
    if (tid < 128) wk[tid] = Wkv[c * 384 + tid];
    __syncthreads();
    if (tid < 128) {
      float acc = 0.f;
      #pragma unroll 8
      for (int j = 0; j < 128; j++) acc += Wq[tid * 128 + j] * wk[j];
      Wt[c * 128 + tid] = (__bf16)acc;
    } else if (tid == 128) {
      float acc = 0.f;
      for (int j = 0; j < 128; j++) acc += bq[j] * wk[j];
      bM[c] = acc;
    }
  } else {
    if (tid < 128) {
      float acc = 0.f;
      for (int j = 0; j < 128; j++) acc += Wq[tid * 128 + j] * bkv[j];
      m2[tid] = acc;
    } else if (tid == 128) {
      float acc = 0.f;
      for (int j = 0; j < 128; j++) acc += bq[j] * bkv[j];
      c0[0] = acc;
    }
  }
}

__global__ __launch_bounds__(1024) void scan1_kernel(const int* __restrict__ cnt, int* __restrict__ off,
                                                     int* __restrict__ bsum, int n) {
  __shared__ int sh[1024];
  int tid = threadIdx.x;
  int i = blockIdx.x * 1024 + tid;
  int v = (i < n) ? cnt[i] : 0;
  sh[tid] = v;
  __syncthreads();
  for (int d = 1; d < 1024; d <<= 1) {
    int t = (tid >= d) ? sh[tid - d] : 0;
    __syncthreads();
    sh[tid] += t;
    __syncthreads();
  }
  if (i < n) off[i] = sh[tid] - v;
  if (tid == 1023) bsum[blockIdx.x] = sh[1023];
}

__global__ __launch_bounds__(1024) void scan3_kernel(const int* __restrict__ bsum, int* __restrict__ off,
                                                     int* __restrict__ cursor, int n, int e) {
  __shared__ int base_sh;
  const int tid = threadIdx.x;
  if (tid < 64) {
    int part = 0;
    for (int b = tid; b < (int)blockIdx.x; b += 64) part += bsum[b];
    #pragma unroll
    for (int m = 32; m >= 1; m >>= 1) part += __shfl_xor(part, m);
    if (tid == 0) base_sh = part;
  }
  __syncthreads();
  const int base = base_sh;
  int i = blockIdx.x * 1024 + tid;
  if (i < n) { int o = off[i] + base; off[i] = o; cursor[i] = o; }
  if (i == 0) off[n] = e;
}

// ---------------- GEMM1 + scatter merged; gemm blocks first; scatter 2 edges/thread ----------------
// gemm1: y=0 -> qM(+beta); y=1 -> sbf | P = (s@Wvv+bvv)*v.  nodebuf/node: [sbf|P0|P1|P2] bf16 = 1024 B

__global__ __launch_bounds__(256) void gemm1_scatter(
    const int* __restrict__ row, const int* __restrict__ col,
    int* __restrict__ cursor, int* __restrict__ scol, int e, int ngemm,
    const float* __restrict__ s, const __bf16* __restrict__ Wtg,
    const float* __restrict__ bM, const float* __restrict__ bkv,
    const float* __restrict__ m2, const float* __restrict__ c0,
    const float* __restrict__ v,
    __bf16* __restrict__ qb, float* __restrict__ beta,
    __bf16* __restrict__ nodebuf, int n)
{
  __shared__ char uB[34816];                 // union: sB (bf16[128][136]) / sO (f32[64][132])
  __bf16* sB = (__bf16*)uB;
  float*  sO = (float*)uB;

  const int tid = threadIdx.x;
  if ((int)blockIdx.x >= ngemm) {            // -------- scatter part: 2 edges/thread --------
    int base = ((int)blockIdx.x - ngemm) * 512;
    int i0 = base + tid;
    int i1 = base + 256 + tid;
    int r0v = 0, c0v = 0, r1v = 0, c1v = 0;
    bool v0 = i0 < e, v1 = i1 < e;
    if (v0) { r0v = row[i0]; c0v = col[i0]; }
    if (v1) { r1v = row[i1]; c1v = col[i1]; }
    int p0 = 0, p1 = 0;
    if (v0) p0 = atomicAdd(&cursor[r0v], 1);
    if (v1) p1 = atomicAdd(&cursor[r1v], 1);
    if (v0) scol[p0] = c0v;
    if (v1) scol[p1] = c1v;
    return;
  }

  const int nb1 = (n + 63) >> 6;
  const int y = ((int)blockIdx.x < nb1) ? 0 : 1;
  const int n0 = (y == 0 ? (int)blockIdx.x : (int)blockIdx.x - nb1) * 64;
  const int wave = tid >> 6, lane = tid & 63;
  const int lr = lane & 15, lg = lane >> 4;
  const int arow = n0 + wave * 16 + lr;

  {
    int r2 = tid >> 1, half = tid & 1;
    int brow = (y == 0) ? r2 : 384 + r2;
    const __bf16* src = &Wtg[(size_t)brow * 128 + half * 64];
    #pragma unroll
    for (int i = 0; i < 8; i++)
      *(bf16x8*)&sB[r2 * 136 + half * 64 + i * 8] = *(const bf16x8*)&src[i * 8];
  }

  bf16x8 a[4];
  if (arow < n) {
    #pragma unroll
    for (int ks = 0; ks < 4; ks++) {
      float4 f0 = *(const float4*)&s[(size_t)arow * 128 + ks * 32 + lg * 8];
      float4 f1 = *(const float4*)&s[(size_t)arow * 128 + ks * 32 + lg * 8 + 4];
      bf16x8 pk;
      pk[0] = (__bf16)f0.x; pk[1] = (__bf16)f0.y; pk[2] = (__bf16)f0.z; pk[3] = (__bf16)f0.w;
      pk[4] = (__bf16)f1.x; pk[5] = (__bf16)f1.y; pk[6] = (__bf16)f1.z; pk[7] = (__bf16)f1.w;
      a[ks] = pk;
    }
  } else {
    #pragma unroll
    for (int ks = 0; ks < 4; ks++) a[ks] = bf16x8{0,0,0,0,0,0,0,0};
  }
  __syncthreads();

  f32x4 acc[8];
  #pragma unroll
  for (int cf = 0; cf < 8; cf++) {
    f32x4 c = {0.f, 0.f, 0.f, 0.f};
    #pragma unroll
    for (int ks = 0; ks < 4; ks++) {
      bf16x8 b = *(const bf16x8*)&sB[(cf * 16 + lr) * 136 + ks * 32 + lg * 8];
      c = __builtin_amdgcn_mfma_f32_16x16x32_bf16(a[ks], b, c, 0, 0, 0);
    }
    acc[cf] = c;
  }
  __syncthreads();

  #pragma unroll
  for (int cf = 0; cf < 8; cf++) {
    int cl = cf * 16 + lr;
    #pragma unroll
    for (int r = 0; r < 4; r++)
      sO[(wave * 16 + lg * 4 + r) * 132 + cl] = acc[cf][r];
  }
  __syncthreads();

  const int drow = tid >> 2, dseg = tid & 3;
  const int dgn = n0 + drow;

  if (y == 0) {
    float part = 0.f;
    #pragma unroll
    for (int ks = 0; ks < 4; ks++)
      #pragma unroll
      for (int j = 0; j < 8; j++)
        part += (float)a[ks][j] * m2[ks * 32 + lg * 8 + j];
    part += __shfl_xor(part, 16);
    part += __shfl_xor(part, 32);
    if (lane < 16 && arow < n) beta[arow] = part + c0[0];

    if (dgn < n) {
      #pragma unroll
      for (int i = 0; i < 4; i++) {
        int cc = dseg * 32 + i * 8;
        bf16x8 pk;
        #pragma unroll
        for (int j = 0; j < 8; j++)
          pk[j] = (__bf16)(sO[drow * 132 + cc + j] + bM[cc + j]);
        *(bf16x8*)&qb[(size_t)dgn * 128 + cc] = pk;
      }
    }
  } else {
    if (arow < n) {
      #pragma unroll
      for (int ks = 0; ks < 4; ks++)
        *(bf16x8*)&nodebuf[(size_t)arow * 512 + ks * 32 + lg * 8] = a[ks];
    }
    if (dgn < n) {
      float vv[32];
      #pragma unroll
      for (int j = 0; j < 32; j++)
        vv[j] = sO[drow * 132 + dseg * 32 + j] + bkv[256 + dseg * 32 + j];
      #pragma unroll
      for (int j3 = 0; j3 < 3; j3++) {
        #pragma unroll
        for (int i = 0; i < 4; i++) {
          int cc = dseg * 32 + i * 8;
          float4 va = *(const float4*)&v[((size_t)dgn * 3 + j3) * 128 + cc];
          float4 vb = *(const float4*)&v[((size_t)dgn * 3 + j3) * 128 + cc + 4];
          bf16x8 pk;
          pk[0] = (__bf16)(vv[i*8+0] * va.x); pk[1] = (__bf16)(vv[i*8+1] * va.y);
          pk[2] = (__bf16)(vv[i*8+2] * va.z); pk[3] = (__bf16)(vv[i*8+3] * va.w);
          pk[4] = (__bf16)(vv[i*8+4] * vb.x); pk[5] = (__bf16)(vv[i*8+5] * vb.y);
          pk[6] = (__bf16)(vv[i*8+6] * vb.z); pk[7] = (__bf16)(vv[i*8+7] * vb.w);
          *(bf16x8*)&nodebuf[(size_t)dgn * 512 + 128 + j3 * 128 + cc] = pk;
        }
      }
    }
  }
}

// ---------------- Aggregation: gather s(bf16)+P(bf16), DPP reduce, depth-1 prefetch ----------------

__device__ inline float2 bf2f(unsigned u) {
  float2 r;
  r.x = __uint_as_float((u & 0xffffu) << 16);
  r.y = __uint_as_float(u & 0xffff0000u);
  return r;
}

__device__ __forceinline__ float dpp_add(float x, const int ctrl) {
  int t;
  switch (ctrl) {
    case 0:  t = __builtin_amdgcn_update_dpp(0, __float_as_int(x), 0xB1, 0xF, 0xF, true); break;
    case 1:  t = __builtin_amdgcn_update_dpp(0, __float_as_int(x), 0x4E, 0xF, 0xF, true); break;
    case 2:  t = __builtin_amdgcn_update_dpp(0, __float_as_int(x), 0x141, 0xF, 0xF, true); break;
    default: t = __builtin_amdgcn_update_dpp(0, __float_as_int(x), 0x140, 0xF, 0xF, true); break;
  }
  return x + __int_as_float(t);
}

__device__ __forceinline__ float row16_sum(float x) {
  x = dpp_add(x, 0); x = dpp_add(x, 1); x = dpp_add(x, 2); x = dpp_add(x, 3);
  return x;
}

#define ACCP(arr, vec) do { float2 _t;                                                \
  _t = bf2f(vec.x); arr[0].x = fmaf(d, _t.x, arr[0].x); arr[0].y = fmaf(d, _t.y, arr[0].y); \
  _t = bf2f(vec.y); arr[1].x = fmaf(d, _t.x, arr[1].x); arr[1].y = fmaf(d, _t.y, arr[1].y); \
  _t = bf2f(vec.z); arr[2].x = fmaf(d, _t.x, arr[2].x); arr[2].y = fmaf(d, _t.y, arr[2].y); \
  _t = bf2f(vec.w); arr[3].x = fmaf(d, _t.x, arr[3].x); arr[3].y = fmaf(d, _t.y, arr[3].y); \
} while (0)

__global__ __launch_bounds__(256) void agg_kernel(
    const int* __restrict__ off, const int* __restrict__ scol,
    const __bf16* __restrict__ qb, const float* __restrict__ beta,
    const char* __restrict__ nodebuf,
    __bf16* __restrict__ gb, float* __restrict__ W1,
    __bf16* __restrict__ aggv16, int n)
{
  const int wid = threadIdx.x >> 6;
  const int lane = threadIdx.x & 63;
  const int nid = blockIdx.x * 4 + wid;
  if (nid >= n) return;
  const int slot = lane >> 4;
  const int fl = lane & 15;

  float qf[8];
  {
    uint4 qu = *(const uint4*)&qb[(size_t)nid * 128 + fl * 8];
    float2 t;
    t = bf2f(qu.x); qf[0] = t.x; qf[1] = t.y;
    t = bf2f(qu.y); qf[2] = t.x; qf[3] = t.y;
    t = bf2f(qu.z); qf[4] = t.x; qf[5] = t.y;
    t = bf2f(qu.w); qf[6] = t.x; qf[7] = t.y;
  }
  const float betar = beta[nid];

  float2 g[4], a0[4], a1[4], a2[4];
  float ws = 0.f;
  #pragma unroll
  for (int i = 0; i < 4; i++) {
    g[i] = make_float2(0.f, 0.f); a0[i] = make_float2(0.f, 0.f);
    a1[i] = make_float2(0.f, 0.f); a2[i] = make_float2(0.f, 0.f);
  }

  const int beg = off[nid];
  const int deg = off[nid + 1] - beg;

  for (int chunk = 0; chunk < deg; chunk += 64) {
    const int cc = (deg - chunk < 64) ? (deg - chunk) : 64;
    int myc = (lane < cc) ? scol[beg + chunk + lane] : 0;

    int c0i = __shfl(myc, (slot < cc) ? slot : 0);
    const char* gp = nodebuf + (size_t)c0i * 1024 + fl * 16;
    uint4 sc = *(const uint4*)(gp);
    uint4 p0 = *(const uint4*)(gp + 256);
    uint4 p1 = *(const uint4*)(gp + 512);
    uint4 p2 = *(const uint4*)(gp + 768);

    for (int j = 0; j < cc; j += 4) {
      const bool more = (j + 4 < cc);
      uint4 nsc, np0, np1, np2;
      if (more) {
        int ni = j + 4 + slot;
        int cn = __shfl(myc, (ni < cc) ? ni : 0);
        const char* gn = nodebuf + (size_t)cn * 1024 + fl * 16;
        nsc = *(const uint4*)(gn);
        np0 = *(const uint4*)(gn + 256);
        np1 = *(const uint4*)(gn + 512);
        np2 = *(const uint4*)(gn + 768);
      }

      float2 t0 = bf2f(sc.x), t1 = bf2f(sc.y), t2 = bf2f(sc.z), t3 = bf2f(sc.w);
      float d = 0.f;
      d = fmaf(qf[0], t0.x, d); d = fmaf(qf[1], t0.y, d);
      d = fmaf(qf[2], t1.x, d); d = fmaf(qf[3], t1.y, d);
      d = fmaf(qf[4], t2.x, d); d = fmaf(qf[5], t2.y, d);
      d = fmaf(qf[6], t3.x, d); d = fmaf(qf[7], t3.y, d);
      d = row16_sum(d) + betar;
      if (j + slot >= cc) d = 0.f;

      g[0].x = fmaf(d, t0.x, g[0].x); g[0].y = fmaf(d, t0.y, g[0].y);
      g[1].x = fmaf(d, t1.x, g[1].x); g[1].y = fmaf(d, t1.y, g[1].y);
      g[2].x = fmaf(d, t2.x, g[2].x); g[2].y = fmaf(d, t2.y, g[2].y);
      g[3].x = fmaf(d, t3.x, g[3].x); g[3].y = fmaf(d, t3.y, g[3].y);
      ws += d;
      ACCP(a0, p0); ACCP(a1, p1); ACCP(a2, p2);

      if (more) { sc = nsc; p0 = np0; p1 = np1; p2 = np2; }
    }
  }

  ws += __shfl_xor(ws, 16); ws += __shfl_xor(ws, 32);
  #pragma unroll
  for (int i = 0; i < 4; i++) {
    g[i].x  += __shfl_xor(g[i].x, 16);  g[i].x  += __shfl_xor(g[i].x, 32);
    g[i].y  += __shfl_xor(g[i].y, 16);  g[i].y  += __shfl_xor(g[i].y, 32);
    a0[i].x += __shfl_xor(a0[i].x, 16); a0[i].x += __shfl_xor(a0[i].x, 32);
    a0[i].y += __shfl_xor(a0[i].y, 16); a0[i].y += __shfl_xor(a0[i].y, 32);
    a1[i].x += __shfl_xor(a1[i].x, 16); a1[i].x += __shfl_xor(a1[i].x, 32);
    a1[i].y += __shfl_xor(a1[i].y, 16); a1[i].y += __shfl_xor(a1[i].y, 32);
    a2[i].x += __shfl_xor(a2[i].x, 16); a2[i].x += __shfl_xor(a2[i].x, 32);
    a2[i].y += __shfl_xor(a2[i].y, 16); a2[i].y += __shfl_xor(a2[i].y, 32);
  }

  if (slot == 0) {
    bf16x8 pk;
    pk[0] = (__bf16)g[0].x; pk[1] = (__bf16)g[0].y; pk[2] = (__bf16)g[1].x; pk[3] = (__bf16)g[1].y;
    pk[4] = (__bf16)g[2].x; pk[5] = (__bf16)g[2].y; pk[6] = (__bf16)g[3].x; pk[7] = (__bf16)g[3].y;
    *(bf16x8*)&gb[(size_t)nid * 128 + fl * 8] = pk;
    if (fl == 0) W1[nid] = ws;

    pk[0] = (__bf16)a0[0].x; pk[1] = (__bf16)a0[0].y; pk[2] = (__bf16)a0[1].x; pk[3] = (__bf16)a0[1].y;
    pk[4] = (__bf16)a0[2].x; pk[5] = (__bf16)a0[2].y; pk[6] = (__bf16)a0[3].x; pk[7] = (__bf16)a0[3].y;
    *(bf16x8*)&aggv16[((size_t)nid * 3 + 0) * 128 + fl * 8] = pk;
    pk[0] = (__bf16)a1[0].x; pk[1] = (__bf16)a1[0].y; pk[2] = (__bf16)a1[1].x; pk[3] = (__bf16)a1[1].y;
    pk[4] = (__bf16)a1[2].x; pk[5] = (__bf16)a1[2].y; pk[6] = (__bf16)a1[3].x; pk[7] = (__bf16)a1[3].y;
    *(bf16x8*)&aggv16[((size_t)nid * 3 + 1) * 128 + fl * 8] = pk;
    pk[0] = (__bf16)a2[0].x; pk[1] = (__bf16)a2[0].y; pk[2] = (__bf16)a2[1].x; pk[3] = (__bf16)a2[1].y;
    pk[4] = (__bf16)a2[2].x; pk[5] = (__bf16)a2[2].y; pk[6] = (__bf16)a2[3].x; pk[7] = (__bf16)a2[3].y;
    *(bf16x8*)&aggv16[((size_t)nid * 3 + 2) * 128 + fl * 8] = pk;
  }
}

// ---------------- GEMM23 (MFMA): s_out = g@Wvs + W1*bvs + s ; vout = aggv@Wvec + v + bvec ----------------

__global__ __launch_bounds__(256) void gemm23_mfma(
    const __bf16* __restrict__ Wtg, const float* __restrict__ bkv, const float* __restrict__ bvec,
    const float* __restrict__ s, const float* __restrict__ v,
    const __bf16* __restrict__ gb, const float* __restrict__ W1,
    const __bf16* __restrict__ aggv16,
    float* __restrict__ s_out, float* __restrict__ vout, int n, int nb1)
{
  __shared__ char uB[34816];
  __bf16* sB = (__bf16*)uB;
  float*  sO = (float*)uB;

  const int tid = threadIdx.x;
  const bool smode = (int)blockIdx.x < nb1;
  const int r0 = smode ? blockIdx.x * 64 : (blockIdx.x - nb1) * 64;
  const int rows = smode ? n : 3 * n;
  const int wave = tid >> 6, lane = tid & 63;
  const int lr = lane & 15, lg = lane >> 4;
  const int arow = r0 + wave * 16 + lr;

  {
    int r2 = tid >> 1, half = tid & 1;
    int brow = (smode ? 256 : 512) + r2;
    const __bf16* src = &Wtg[(size_t)brow * 128 + half * 64];
    #pragma unroll
    for (int i = 0; i < 8; i++)
      *(bf16x8*)&sB[r2 * 136 + half * 64 + i * 8] = *(const bf16x8*)&src[i * 8];
  }

  const __bf16* Asrc = smode ? gb : aggv16;
  bf16x8 a[4];
  if (arow < rows) {
    #pragma unroll
    for (int ks = 0; ks < 4; ks++)
      a[ks] = *(const bf16x8*)&Asrc[(size_t)arow * 128 + ks * 32 + lg * 8];
  } else {
    #pragma unroll
    for (int ks = 0; ks < 4; ks++) a[ks] = bf16x8{0,0,0,0,0,0,0,0};
  }
  __syncthreads();

  f32x4 acc[8];
  #pragma unroll
  for (int cf = 0; cf < 8; cf++) {
    f32x4 c = {0.f, 0.f, 0.f, 0.f};
    #pragma unroll
    for (int ks = 0; ks < 4; ks++) {
      bf16x8 b = *(const bf16x8*)&sB[(cf * 16 + lr) * 136 + ks * 32 + lg * 8];
      c = __builtin_amdgcn_mfma_f32_16x16x32_bf16(a[ks], b, c, 0, 0, 0);
    }
    acc[cf] = c;
  }
  __syncthreads();

  #pragma unroll
  for (int cf = 0; cf < 8; cf++) {
    int cl = cf * 16 + lr;
    #pragma unroll
    for (int r = 0; r < 4; r++)
      sO[(wave * 16 + lg * 4 + r) * 132 + cl] = acc[cf][r];
  }
  __syncthreads();

  const int drow = tid >> 2, dseg = tid & 3;
  const int dgr = r0 + drow;

  if (dgr < rows) {
    if (smode) {
      const float w1 = W1[dgr];
      #pragma unroll
      for (int i = 0; i < 8; i++) {
        int cc = dseg * 32 + i * 4;
        float4 sa = *(const float4*)&s[(size_t)dgr * 128 + cc];
        float4 o;
        o.x = sO[drow * 132 + cc + 0] + sa.x + w1 * bkv[128 + cc + 0];
        o.y = sO[drow * 132 + cc + 1] + sa.y + w1 * bkv[128 + cc + 1];
        o.z = sO[drow * 132 + cc + 2] + sa.z + w1 * bkv[128 + cc + 2];
        o.w = sO[drow * 132 + cc + 3] + sa.w + w1 * bkv[128 + cc + 3];
        *(float4*)&s_out[(size_t)dgr * 128 + cc] = o;
      }
    } else {
      #pragma unroll
      for (int i = 0; i < 8; i++) {
        int cc = dseg * 32 + i * 4;
        float4 va = *(const float4*)&v[(size_t)dgr * 128 + cc];
        float4 o;
        o.x = sO[drow * 132 + cc + 0] + va.x + bvec[cc + 0];
        o.y = sO[drow * 132 + cc + 1] + va.y + bvec[cc + 1];
        o.z = sO[drow * 132 + cc + 2] + va.z + bvec[cc + 2];
        o.w = sO[drow * 132 + cc + 3] + va.w + bvec[cc + 3];
        *(float4*)&vout[(size_t)dgr * 128 + cc] = o;
      }
    }
  }
}

// ---------------- launch ----------------

extern "C" void kernel_launch(void* const* d_in, const int* in_sizes, int n_in,
                              void* d_out, int out_size, void* d_ws, size_t ws_size,
                              hipStream_t stream)
{
  const float* s    = (const float*)d_in[0];
  const float* v    = (const float*)d_in[1];
  const int*   ei   = (const int*)d_in[2];
  const float* Wq   = (const float*)d_in[3];
  const float* bq   = (const float*)d_in[4];
  const float* Wkv  = (const float*)d_in[5];
  const float* bkv  = (const float*)d_in[6];
  const float* Wvec = (const float*)d_in[7];
  const float* bvec = (const float*)d_in[8];

  const int N = in_sizes[0] / 128;
  const int E = in_sizes[2] / 2;
  const int* row = ei;
  const int* col = ei + E;

  char* ws = (char*)d_ws;
  size_t o = 0;
  auto alloc = [&](size_t bytes) -> char* {
    char* p = ws + o;
    o = (o + bytes + 255) & ~(size_t)255;
    return p;
  };
  int* off    = (int*)alloc((size_t)(N + 1) * 4);
  int* cursor = (int*)alloc((size_t)N * 4);
  int* bsum   = (int*)alloc(4096);
  int* scol   = (int*)alloc((size_t)E * 4);
  __bf16* qb      = (__bf16*)alloc((size_t)N * 128 * 2);
  float*  beta    = (float*)alloc((size_t)N * 4);
  float*  W1      = (float*)alloc((size_t)N * 4);
  __bf16* nodebuf = (__bf16*)alloc((size_t)N * 512 * 2);
  __bf16* Wt      = (__bf16*)alloc((size_t)640 * 128 * 2);
  __bf16* aggv16  = (__bf16*)alloc((size_t)N * 384 * 2);
  __bf16* gb      = (__bf16*)alloc((size_t)N * 128 * 2);
  float*  bM      = (float*)alloc(512);
  float*  m2      = (float*)alloc(512);
  float*  c0      = (float*)alloc(256);

  float* s_out = (float*)d_out;
  float* vout  = (float*)d_out + (size_t)N * 128;

  // prep: hist + W transpose + M^T + m2/c0
  (void)hipMemsetAsync(cursor, 0, (size_t)N * 4, stream);
  int nbh = (E + 255) / 256;
  prep_kernel<<<nbh + 256 + 128 + 1, 256, 0, stream>>>(row, cursor, E, Wq, Wkv, Wvec, bq, bkv,
                                                       Wt, bM, m2, c0, nbh);
  int nb = (N + 1023) / 1024;
  scan1_kernel<<<nb, 1024, 0, stream>>>(cursor, off, bsum, N);
  scan3_kernel<<<nb, 1024, 0, stream>>>(bsum, off, cursor, N, E);

  // gemm1 + scatter (merged; gemm blocks first; scatter 2 edges/thread)
  int nb1 = (N + 63) / 64;
  int ngemm = 2 * nb1;
  int nbs_sc = (E + 511) / 512;
  gemm1_scatter<<<ngemm + nbs_sc, 256, 0, stream>>>(row, col, cursor, scol, E, ngemm,
                                                    s, Wt, bM, bkv, m2, c0, v,
                                                    qb, beta, nodebuf, N);

  // edge aggregation
  agg_kernel<<<(N + 3) / 4, 256, 0, stream>>>(off, scol, qb, beta, (const char*)nodebuf,
                                              gb, W1, aggv16, N);

  // fused output GEMMs
  int nb2 = (3 * N + 63) / 64;
  gemm23_mfma<<<nb1 + nb2, 256, 0, stream>>>(Wt, bkv, bvec, s, v, gb, W1, aggv16,
                                             s_out, vout, N, nb1);
}